// Round 3
// baseline (650.837 us; speedup 1.0000x reference)
//
#include <hip/hip_runtime.h>
#include <hip/hip_bf16.h>

// ---------------------------------------------------------------------------
// DynamicTransformer, round 3 = round 2 + prepw grid fix.
//
// Round-2 bug: dt_prepw launched 16384 threads but needs 8192 (wiA) + 16384
// (woB) = 24576 -> woB channel blocks cc=4..7 stayed 0xAA poison -> proj_out
// summed only half its K dim (absmax 0.039 ~ 0.7x output scale). Fix: 96
// blocks.
//
//  prepw : w_in / w_out -> bf16 in exact MFMA fragment order (global)
//  prepx : x (b,c,y,x) f32 -> xT (b, y+1, x+1, c) bf16 with zero border,
//          fused per-(b,c) channel sums (for the kernel generator)
//  kgen  : exact-fp32 dynamic kernel generator -> karr[b][tap][o]
//  kmain : 16x16 aligned output tiles; h lives in f32 registers between
//          proj_in MFMA and the depthwise conv (L/M/R column-shifted
//          fragments give x-neighbors, rolling 3-row window gives
//          y-neighbors); y feeds proj_out MFMA directly as A-fragment.
//          One barrier for compute; stores bounce through LDS for aligned
//          64B f32x4 rows.
// ---------------------------------------------------------------------------

typedef __bf16 bf16;
typedef __bf16 bf16x4 __attribute__((ext_vector_type(4)));
typedef __bf16 bf16x8 __attribute__((ext_vector_type(8)));
typedef float  f32x4  __attribute__((ext_vector_type(4)));

#define B_   8
#define DIM_ 64
#define HID_ 128
#define HW_  192
#define PW_  194            // padded width/height of xT

__device__ __forceinline__ void gl_lds16(const void* g, void* l) {
  __builtin_amdgcn_global_load_lds((__attribute__((address_space(1))) void*)(g),
                                   (__attribute__((address_space(3))) void*)(l),
                                   16, 0, 0);
}

// ws layout (bytes)
#define WS_XT    0u            // 8*194*194*64*2 = 38,539,264
#define WS_XSUM  38539264u     // 512 f32
#define WS_KARR  38541312u     // 8 * 9*128 f32 = 36,864
#define WS_WIA   38578176u     // 8192 bf16 = 16,384
#define WS_WOB   38594560u     // 16384 bf16 = 32,768

// ---------------------------------------------------------------------------
// prepw: w_in -> A-frag order [cc][kk][q][m][j] (o=16cc+m, c=32kk+8q+j)
//        w_out -> B-frag order [cc][q][j64][slot8] (slot<4: w_out[j][16cc+4q+slot], else 0)
// 24576 threads: 8192 for wiA, 16384 for woB.
// ---------------------------------------------------------------------------
__global__ __launch_bounds__(256) void dt_prepw(const float* __restrict__ w_in,
                                                const float* __restrict__ w_out,
                                                bf16* __restrict__ wiA,
                                                bf16* __restrict__ woB) {
  int i = blockIdx.x * 256 + threadIdx.x;          // 0..24575
  if (i < 8192) {
    int j = i & 7, m = (i >> 3) & 15, q = (i >> 7) & 3, kk = (i >> 9) & 1, cc = i >> 10;
    int o = cc * 16 + m, c = kk * 32 + q * 8 + j;
    wiA[i] = (bf16)w_in[o * DIM_ + c];
  } else {
    int i2 = i - 8192;                             // 0..16383
    int sl = i2 & 7, j = (i2 >> 3) & 63, q = (i2 >> 9) & 3, cc = i2 >> 11;  // cc 0..7
    float v = (sl < 4) ? w_out[j * HID_ + cc * 16 + q * 4 + sl] : 0.f;
    woB[i2] = (bf16)v;
  }
}

// ---------------------------------------------------------------------------
// prepx: one block per (b, padded row yy). Interior rows: transpose 64x192
// f32 -> 192 px * 64c bf16 (via LDS), plus channel partial sums -> atomicAdd.
// Border rows / cols written as zeros.
// ---------------------------------------------------------------------------
__global__ __launch_bounds__(256) void dt_prepx(const float* __restrict__ x,
                                                bf16* __restrict__ xT,
                                                float* __restrict__ xsum) {
  const int yy = blockIdx.x, b = blockIdx.y, t = threadIdx.x;
  bf16* xtrow = xT + ((size_t)(b * PW_ + yy)) * PW_ * DIM_;
  const bf16x8 z8 = {(bf16)0.f,(bf16)0.f,(bf16)0.f,(bf16)0.f,
                     (bf16)0.f,(bf16)0.f,(bf16)0.f,(bf16)0.f};
  if (yy == 0 || yy == PW_ - 1) {
    if (t < PW_) {
      bf16* dst = xtrow + t * DIM_;
#pragma unroll
      for (int c8 = 0; c8 < 8; ++c8) *(bf16x8*)(dst + c8 * 8) = z8;
    }
    return;
  }
  const int y = yy - 1;
  __shared__ float xr[DIM_ * HW_];                 // [c][px]
  const int c = t >> 2, qu = t & 3;
  const float4* rp = (const float4*)(x + ((size_t)(b * DIM_ + c) * HW_ + y) * HW_) + qu * 12;
  float s = 0.f;
#pragma unroll
  for (int i = 0; i < 12; ++i) {
    float4 v = rp[i];
    s += (v.x + v.y) + (v.z + v.w);
    ((float4*)xr)[c * 48 + qu * 12 + i] = v;
  }
  s += __shfl_down(s, 2);
  s += __shfl_down(s, 1);
  if ((t & 3) == 0) atomicAdd(xsum + b * DIM_ + c, s);
  __syncthreads();
  if (t < HW_) {
    const int px = t;
    bf16* dst = xtrow + (px + 1) * DIM_;
#pragma unroll
    for (int c8 = 0; c8 < 8; ++c8) {
      bf16x8 pk;
#pragma unroll
      for (int j2 = 0; j2 < 8; ++j2) pk[j2] = (bf16)xr[(c8 * 8 + j2) * HW_ + px];
      *(bf16x8*)(dst + c8 * 8) = pk;
    }
  } else if (t == HW_ || t == HW_ + 1) {           // border cols xx=0, xx=193
    bf16* dst = xtrow + (size_t)(t - HW_) * (PW_ - 1) * DIM_;
#pragma unroll
    for (int c8 = 0; c8 < 8; ++c8) *(bf16x8*)(dst + c8 * 8) = z8;
  }
}

// ---------------------------------------------------------------------------
// kgen: exact fp32. karr[b][tap][o], tap-major so kmain reads f32x4 over o.
// ---------------------------------------------------------------------------
__global__ __launch_bounds__(128) void dt_kgen(
    const float* __restrict__ xsum, const float* __restrict__ w_in,
    const float* __restrict__ b_in, const float* __restrict__ wg1,
    const float* __restrict__ bg1, const float* __restrict__ wg2,
    const float* __restrict__ bg2, float* __restrict__ karr) {
  const int b = blockIdx.x, t = threadIdx.x;
  __shared__ float xm[DIM_], hm[HID_], g[HID_];
  if (t < DIM_) xm[t] = xsum[b * DIM_ + t] * (1.f / (HW_ * HW_));
  __syncthreads();
  {
    float a = b_in[t];
    const float* w = w_in + t * DIM_;
    for (int c = 0; c < DIM_; ++c) a += w[c] * xm[c];
    hm[t] = a;
  }
  __syncthreads();
  {
    float a = bg1[t];
    const float* w = wg1 + t * HID_;
    for (int c = 0; c < HID_; ++c) a += w[c] * hm[c];
    g[t] = a > 0.f ? a : 0.f;
  }
  __syncthreads();
  for (int tp = 0; tp < 9; ++tp) {
    float s = bg2[t * 9 + tp];
    const float* w2 = wg2 + (size_t)(t * 9 + tp) * HID_;
    for (int c = 0; c < HID_; ++c) s += w2[c] * g[c];
    karr[b * 1152 + tp * HID_ + t] = s;
  }
}

// ---------------------------------------------------------------------------
// kmain. Grid (12,12,8), 256 threads (4 waves). Wave wv owns out rows
// 4wv..4wv+3 of the tile (h tile rows 4wv..4wv+5).
// LDS: [0,41472) x_s: 18 rows x (kk2 x q4 x px18) 16B chunks
//      [41472,46080) karr f32 [tap][128]
//      store bounce aliases [0,34048) after compute barrier.
// ---------------------------------------------------------------------------
#define XROWB 2304
#define KOFF  41472

__global__ __launch_bounds__(256, 3) void dt_kmain(
    const bf16* __restrict__ xT, const bf16* __restrict__ wiA,
    const bf16* __restrict__ woB, const float* __restrict__ karr,
    const float* __restrict__ b_in, const float* __restrict__ b_out,
    float* __restrict__ out) {
  __shared__ __attribute__((aligned(16))) char smem[46080];
  const int t = threadIdx.x;
  const int wv = t >> 6, lane = t & 63;
  const int q = lane >> 4, m = lane & 15;
  const int tx = blockIdx.x, ty = blockIdx.y, b = blockIdx.z;

  // ---- stage x tile + karr via global_load_lds ---------------------------
  {
    const char* xbase = (const char*)xT +
        ((size_t)(b * PW_ + ty * 16) * PW_ + tx * 16) * (DIM_ * 2);
    for (int rr = wv; rr < 18; rr += 4) {
      const char* grow = xbase + (size_t)rr * (PW_ * DIM_ * 2);
      char* lrow = smem + rr * XROWB;
#pragma unroll
      for (int p = 0; p < 3; ++p) {
        int idx = p * 64 + lane;
        if (idx < 144) {
          int kq = (idx * 57) >> 10;        // idx / 18
          int px = idx - kq * 18;
          int goff = px * 128 + (kq >> 2) * 64 + (kq & 3) * 16;
          gl_lds16(grow + goff, lrow + p * 1024);
        }
      }
    }
    const char* kg = (const char*)karr + b * 4608;
    gl_lds16(kg + (wv * 64 + lane) * 16, smem + KOFF + wv * 1024);
    if (wv == 0 && lane < 32)
      gl_lds16(kg + (256 + lane) * 16, smem + KOFF + 4096);
  }
  __syncthreads();

  const int rowg0 = ty * 16 - 1;
  const int colg0 = tx * 16 - 1;
  const float mL = ((unsigned)(colg0 + 0 + m) < (unsigned)HW_) ? 1.f : 0.f;
  const float mM = ((unsigned)(colg0 + 1 + m) < (unsigned)HW_) ? 1.f : 0.f;
  const float mR = ((unsigned)(colg0 + 2 + m) < (unsigned)HW_) ? 1.f : 0.f;

  f32x4 acc3[4][4];
#pragma unroll
  for (int a = 0; a < 4; ++a)
#pragma unroll
    for (int n = 0; n < 4; ++n) acc3[a][n] = 0.f;

  const float* karrL = (const float*)(smem + KOFF);

  for (int cc = 0; cc < 8; ++cc) {
    const bf16x8 wa0 = *(const bf16x8*)((const char*)wiA + ((cc * 2 + 0) * 4 + q) * 256 + m * 16);
    const bf16x8 wa1 = *(const bf16x8*)((const char*)wiA + ((cc * 2 + 1) * 4 + q) * 256 + m * 16);
    const f32x4 bin4 = *(const f32x4*)(b_in + cc * 16 + q * 4);
    f32x4 kv[9];
#pragma unroll
    for (int tp = 0; tp < 9; ++tp)
      kv[tp] = *(const f32x4*)(karrL + tp * HID_ + cc * 16 + q * 4);

    f32x4 hwin[3][3];
#pragma unroll
    for (int rr = 0; rr < 6; ++rr) {
      const int row = wv * 4 + rr;
      const char* rbase = smem + row * XROWB + q * 288 + m * 16;
      bf16x8 x0L = *(const bf16x8*)(rbase);
      bf16x8 x0M = *(const bf16x8*)(rbase + 16);
      bf16x8 x0R = *(const bf16x8*)(rbase + 32);
      bf16x8 x1L = *(const bf16x8*)(rbase + 1152);
      bf16x8 x1M = *(const bf16x8*)(rbase + 1152 + 16);
      bf16x8 x1R = *(const bf16x8*)(rbase + 1152 + 32);
      f32x4 z = 0.f;
      f32x4 hL = __builtin_amdgcn_mfma_f32_16x16x32_bf16(wa0, x0L, z, 0, 0, 0);
      hL = __builtin_amdgcn_mfma_f32_16x16x32_bf16(wa1, x1L, hL, 0, 0, 0);
      f32x4 hM = __builtin_amdgcn_mfma_f32_16x16x32_bf16(wa0, x0M, z, 0, 0, 0);
      hM = __builtin_amdgcn_mfma_f32_16x16x32_bf16(wa1, x1M, hM, 0, 0, 0);
      f32x4 hR = __builtin_amdgcn_mfma_f32_16x16x32_bf16(wa0, x0R, z, 0, 0, 0);
      hR = __builtin_amdgcn_mfma_f32_16x16x32_bf16(wa1, x1R, hR, 0, 0, 0);
      if ((unsigned)(rowg0 + row) < (unsigned)HW_) {   // wave-uniform
        hL += bin4 * mL;
        hM += bin4 * mM;
        hR += bin4 * mR;
      }
      const int slot = rr % 3;
      hwin[slot][0] = hL; hwin[slot][1] = hM; hwin[slot][2] = hR;

      if (rr >= 2) {
        const int py = rr - 2;
        const int s0 = py % 3, s1 = (py + 1) % 3, s2 = (py + 2) % 3;
        // proj_out B-frags (lazy, latency hidden by the dw compute)
        bf16x8 wb0 = *(const bf16x8*)((const char*)woB + (((cc * 4 + q) * 64) + 0 * 16 + m) * 16);
        bf16x8 wb1 = *(const bf16x8*)((const char*)woB + (((cc * 4 + q) * 64) + 1 * 16 + m) * 16);
        bf16x8 wb2 = *(const bf16x8*)((const char*)woB + (((cc * 4 + q) * 64) + 2 * 16 + m) * 16);
        bf16x8 wb3 = *(const bf16x8*)((const char*)woB + (((cc * 4 + q) * 64) + 3 * 16 + m) * 16);
        bf16 yf[4];
#pragma unroll
        for (int r = 0; r < 4; ++r) {
          float v = kv[0][r] * hwin[s0][0][r] + kv[1][r] * hwin[s0][1][r] +
                    kv[2][r] * hwin[s0][2][r] + kv[3][r] * hwin[s1][0][r] +
                    kv[4][r] * hwin[s1][1][r] + kv[5][r] * hwin[s1][2][r] +
                    kv[6][r] * hwin[s2][0][r] + kv[7][r] * hwin[s2][1][r] +
                    kv[8][r] * hwin[s2][2][r];
          v = fmaxf(v, 0.1f * v);                     // LeakyReLU(0.1)
          yf[r] = (bf16)v;
        }
        bf16x8 af = {yf[0], yf[1], yf[2], yf[3],
                     (bf16)0.f, (bf16)0.f, (bf16)0.f, (bf16)0.f};
        acc3[py][0] = __builtin_amdgcn_mfma_f32_16x16x32_bf16(af, wb0, acc3[py][0], 0, 0, 0);
        acc3[py][1] = __builtin_amdgcn_mfma_f32_16x16x32_bf16(af, wb1, acc3[py][1], 0, 0, 0);
        acc3[py][2] = __builtin_amdgcn_mfma_f32_16x16x32_bf16(af, wb2, acc3[py][2], 0, 0, 0);
        acc3[py][3] = __builtin_amdgcn_mfma_f32_16x16x32_bf16(af, wb3, acc3[py][3], 0, 0, 0);
      }
    }
  }
  __syncthreads();          // x_s / karr dead; bounce region reuses smem

  // ---- store via LDS bounce: aligned 64B f32x4 rows ----------------------
  float* smemF = (float*)smem;                      // [j][132] f32, halves of 8 rows
  const int c4 = t & 3, js = (t >> 2) & 63;
  const float bo = b_out[js];
  float* obase = out + ((size_t)(b * DIM_ + js) * HW_ + (ty * 16)) * HW_ + tx * 16 + c4 * 4;
#pragma unroll
  for (int half = 0; half < 2; ++half) {
    if ((wv >> 1) == half) {
#pragma unroll
      for (int py = 0; py < 4; ++py) {
        const int lrow = (wv * 4 + py) & 7;
#pragma unroll
        for (int nt = 0; nt < 4; ++nt)
          *(f32x4*)(smemF + (nt * 16 + m) * 132 + lrow * 16 + q * 4) = acc3[py][nt];
      }
    }
    __syncthreads();
#pragma unroll
    for (int lrow = 0; lrow < 8; ++lrow) {
      f32x4 v = *(const f32x4*)(smemF + js * 132 + lrow * 16 + c4 * 4);
      v += bo;
      *(f32x4*)(obase + (size_t)(half * 8 + lrow) * HW_) = v;
    }
    __syncthreads();
  }
}

// ---------------------------------------------------------------------------
extern "C" void kernel_launch(void* const* d_in, const int* in_sizes, int n_in,
                              void* d_out, int out_size, void* d_ws,
                              size_t ws_size, hipStream_t stream) {
  const float* x     = (const float*)d_in[0];
  const float* w_in  = (const float*)d_in[1];
  const float* b_in  = (const float*)d_in[2];
  const float* wg1   = (const float*)d_in[3];
  const float* bg1   = (const float*)d_in[4];
  const float* wg2   = (const float*)d_in[5];
  const float* bg2   = (const float*)d_in[6];
  const float* w_out = (const float*)d_in[7];
  const float* b_out = (const float*)d_in[8];
  float* out = (float*)d_out;

  char* ws = (char*)d_ws;
  bf16*  xT   = (bf16*)(ws + WS_XT);
  float* xsum = (float*)(ws + WS_XSUM);
  float* karr = (float*)(ws + WS_KARR);
  bf16*  wiA  = (bf16*)(ws + WS_WIA);
  bf16*  woB  = (bf16*)(ws + WS_WOB);

  hipMemsetAsync(xsum, 0, B_ * DIM_ * sizeof(float), stream);
  dt_prepw<<<dim3(96), dim3(256), 0, stream>>>(w_in, w_out, wiA, woB);
  dt_prepx<<<dim3(PW_, B_), dim3(256), 0, stream>>>(x, xT, xsum);
  dt_kgen<<<dim3(B_), dim3(128), 0, stream>>>(xsum, w_in, b_in, wg1, bg1, wg2,
                                              bg2, karr);
  dt_kmain<<<dim3(12, 12, B_), dim3(256), 0, stream>>>(xT, wiA, woB, karr,
                                                       b_in, b_out, out);
}

// Round 4
// 372.769 us; speedup vs baseline: 1.7460x; 1.7460x over previous
//
#include <hip/hip_runtime.h>
#include <hip/hip_bf16.h>

// ---------------------------------------------------------------------------
// DynamicTransformer, round 4 = round 3 + spill fix.
//
// Round-3 diagnosis: __launch_bounds__(256,3) capped the unified VGPR budget
// at ~170 while the cc-loop live set is ~230 -> compiler split 84 arch + 86
// acc (VGPR_Count=84 signature) and spilled kv/hwin/wb to scratch every
// iteration: ~3 KB/thread round-trip = ~875 MB write + ~875 MB read = the
// observed 2.0 GB HBM traffic and 535 us. Fix: (256,2) -> 256-reg budget
// (2 blocks/CU), and hoist the py-invariant woB fragments to per-cc.
//
//  prepw : w_in / w_out -> bf16 in exact MFMA fragment order (global)
//  prepx : x (b,c,y,x) f32 -> xT (b, y+1, x+1, c) bf16 with zero border,
//          fused per-(b,c) channel sums (for the kernel generator)
//  kgen  : exact-fp32 dynamic kernel generator -> karr[b][tap][o]
//  kmain : 16x16 aligned output tiles; h lives in f32 registers between
//          proj_in MFMA and the depthwise conv; one barrier for compute;
//          stores bounce through LDS for aligned 64B f32x4 rows.
// ---------------------------------------------------------------------------

typedef __bf16 bf16;
typedef __bf16 bf16x4 __attribute__((ext_vector_type(4)));
typedef __bf16 bf16x8 __attribute__((ext_vector_type(8)));
typedef float  f32x4  __attribute__((ext_vector_type(4)));

#define B_   8
#define DIM_ 64
#define HID_ 128
#define HW_  192
#define PW_  194            // padded width/height of xT

__device__ __forceinline__ void gl_lds16(const void* g, void* l) {
  __builtin_amdgcn_global_load_lds((__attribute__((address_space(1))) void*)(g),
                                   (__attribute__((address_space(3))) void*)(l),
                                   16, 0, 0);
}

// ws layout (bytes)
#define WS_XT    0u            // 8*194*194*64*2 = 38,539,264
#define WS_XSUM  38539264u     // 512 f32
#define WS_KARR  38541312u     // 8 * 9*128 f32 = 36,864
#define WS_WIA   38578176u     // 8192 bf16 = 16,384
#define WS_WOB   38594560u     // 16384 bf16 = 32,768

// ---------------------------------------------------------------------------
// prepw: w_in -> A-frag order [cc][kk][q][m][j] (o=16cc+m, c=32kk+8q+j)
//        w_out -> B-frag order [cc][q][j64][slot8] (slot<4: w_out[j][16cc+4q+slot], else 0)
// 24576 threads: 8192 for wiA, 16384 for woB.
// ---------------------------------------------------------------------------
__global__ __launch_bounds__(256) void dt_prepw(const float* __restrict__ w_in,
                                                const float* __restrict__ w_out,
                                                bf16* __restrict__ wiA,
                                                bf16* __restrict__ woB) {
  int i = blockIdx.x * 256 + threadIdx.x;          // 0..24575
  if (i < 8192) {
    int j = i & 7, m = (i >> 3) & 15, q = (i >> 7) & 3, kk = (i >> 9) & 1, cc = i >> 10;
    int o = cc * 16 + m, c = kk * 32 + q * 8 + j;
    wiA[i] = (bf16)w_in[o * DIM_ + c];
  } else {
    int i2 = i - 8192;                             // 0..16383
    int sl = i2 & 7, j = (i2 >> 3) & 63, q = (i2 >> 9) & 3, cc = i2 >> 11;  // cc 0..7
    float v = (sl < 4) ? w_out[j * HID_ + cc * 16 + q * 4 + sl] : 0.f;
    woB[i2] = (bf16)v;
  }
}

// ---------------------------------------------------------------------------
// prepx: one block per (b, padded row yy). Interior rows: transpose 64x192
// f32 -> 192 px * 64c bf16 (via LDS), plus channel partial sums -> atomicAdd.
// Border rows / cols written as zeros.
// ---------------------------------------------------------------------------
__global__ __launch_bounds__(256) void dt_prepx(const float* __restrict__ x,
                                                bf16* __restrict__ xT,
                                                float* __restrict__ xsum) {
  const int yy = blockIdx.x, b = blockIdx.y, t = threadIdx.x;
  bf16* xtrow = xT + ((size_t)(b * PW_ + yy)) * PW_ * DIM_;
  const bf16x8 z8 = {(bf16)0.f,(bf16)0.f,(bf16)0.f,(bf16)0.f,
                     (bf16)0.f,(bf16)0.f,(bf16)0.f,(bf16)0.f};
  if (yy == 0 || yy == PW_ - 1) {
    if (t < PW_) {
      bf16* dst = xtrow + t * DIM_;
#pragma unroll
      for (int c8 = 0; c8 < 8; ++c8) *(bf16x8*)(dst + c8 * 8) = z8;
    }
    return;
  }
  const int y = yy - 1;
  __shared__ float xr[DIM_ * HW_];                 // [c][px]
  const int c = t >> 2, qu = t & 3;
  const float4* rp = (const float4*)(x + ((size_t)(b * DIM_ + c) * HW_ + y) * HW_) + qu * 12;
  float s = 0.f;
#pragma unroll
  for (int i = 0; i < 12; ++i) {
    float4 v = rp[i];
    s += (v.x + v.y) + (v.z + v.w);
    ((float4*)xr)[c * 48 + qu * 12 + i] = v;
  }
  s += __shfl_down(s, 2);
  s += __shfl_down(s, 1);
  if ((t & 3) == 0) atomicAdd(xsum + b * DIM_ + c, s);
  __syncthreads();
  if (t < HW_) {
    const int px = t;
    bf16* dst = xtrow + (px + 1) * DIM_;
#pragma unroll
    for (int c8 = 0; c8 < 8; ++c8) {
      bf16x8 pk;
#pragma unroll
      for (int j2 = 0; j2 < 8; ++j2) pk[j2] = (bf16)xr[(c8 * 8 + j2) * HW_ + px];
      *(bf16x8*)(dst + c8 * 8) = pk;
    }
  } else if (t == HW_ || t == HW_ + 1) {           // border cols xx=0, xx=193
    bf16* dst = xtrow + (size_t)(t - HW_) * (PW_ - 1) * DIM_;
#pragma unroll
    for (int c8 = 0; c8 < 8; ++c8) *(bf16x8*)(dst + c8 * 8) = z8;
  }
}

// ---------------------------------------------------------------------------
// kgen: exact fp32. karr[b][tap][o], tap-major so kmain reads f32x4 over o.
// ---------------------------------------------------------------------------
__global__ __launch_bounds__(128) void dt_kgen(
    const float* __restrict__ xsum, const float* __restrict__ w_in,
    const float* __restrict__ b_in, const float* __restrict__ wg1,
    const float* __restrict__ bg1, const float* __restrict__ wg2,
    const float* __restrict__ bg2, float* __restrict__ karr) {
  const int b = blockIdx.x, t = threadIdx.x;
  __shared__ float xm[DIM_], hm[HID_], g[HID_];
  if (t < DIM_) xm[t] = xsum[b * DIM_ + t] * (1.f / (HW_ * HW_));
  __syncthreads();
  {
    float a = b_in[t];
    const float* w = w_in + t * DIM_;
    for (int c = 0; c < DIM_; ++c) a += w[c] * xm[c];
    hm[t] = a;
  }
  __syncthreads();
  {
    float a = bg1[t];
    const float* w = wg1 + t * HID_;
    for (int c = 0; c < HID_; ++c) a += w[c] * hm[c];
    g[t] = a > 0.f ? a : 0.f;
  }
  __syncthreads();
  for (int tp = 0; tp < 9; ++tp) {
    float s = bg2[t * 9 + tp];
    const float* w2 = wg2 + (size_t)(t * 9 + tp) * HID_;
    for (int c = 0; c < HID_; ++c) s += w2[c] * g[c];
    karr[b * 1152 + tp * HID_ + t] = s;
  }
}

// ---------------------------------------------------------------------------
// kmain. Grid (12,12,8), 256 threads (4 waves). Wave wv owns out rows
// 4wv..4wv+3 of the tile (h tile rows 4wv..4wv+5).
// LDS: [0,41472) x_s: 18 rows x (kk2 x q4 x px18) 16B chunks
//      [41472,46080) karr f32 [tap][128]
//      store bounce aliases [0,34048) after compute barrier.
// __launch_bounds__(256,2): 256-VGPR unified budget; the cc-loop live set
// (~230 regs: acc3 64 + kv 36 + hwin 36 + wa 16 + wb 32 + addr) must fit
// with NO scratch spill — (256,3) spilled ~3 KB/thread = 2 GB of HBM.
// ---------------------------------------------------------------------------
#define XROWB 2304
#define KOFF  41472

__global__ __launch_bounds__(256, 2) void dt_kmain(
    const bf16* __restrict__ xT, const bf16* __restrict__ wiA,
    const bf16* __restrict__ woB, const float* __restrict__ karr,
    const float* __restrict__ b_in, const float* __restrict__ b_out,
    float* __restrict__ out) {
  __shared__ __attribute__((aligned(16))) char smem[46080];
  const int t = threadIdx.x;
  const int wv = t >> 6, lane = t & 63;
  const int q = lane >> 4, m = lane & 15;
  const int tx = blockIdx.x, ty = blockIdx.y, b = blockIdx.z;

  // ---- stage x tile + karr via global_load_lds ---------------------------
  {
    const char* xbase = (const char*)xT +
        ((size_t)(b * PW_ + ty * 16) * PW_ + tx * 16) * (DIM_ * 2);
    for (int rr = wv; rr < 18; rr += 4) {
      const char* grow = xbase + (size_t)rr * (PW_ * DIM_ * 2);
      char* lrow = smem + rr * XROWB;
#pragma unroll
      for (int p = 0; p < 3; ++p) {
        int idx = p * 64 + lane;
        if (idx < 144) {
          int kq = (idx * 57) >> 10;        // idx / 18
          int px = idx - kq * 18;
          int goff = px * 128 + (kq >> 2) * 64 + (kq & 3) * 16;
          gl_lds16(grow + goff, lrow + p * 1024);
        }
      }
    }
    const char* kg = (const char*)karr + b * 4608;
    gl_lds16(kg + (wv * 64 + lane) * 16, smem + KOFF + wv * 1024);
    if (wv == 0 && lane < 32)
      gl_lds16(kg + (256 + lane) * 16, smem + KOFF + 4096);
  }
  __syncthreads();

  const int rowg0 = ty * 16 - 1;
  const int colg0 = tx * 16 - 1;
  const float mL = ((unsigned)(colg0 + 0 + m) < (unsigned)HW_) ? 1.f : 0.f;
  const float mM = ((unsigned)(colg0 + 1 + m) < (unsigned)HW_) ? 1.f : 0.f;
  const float mR = ((unsigned)(colg0 + 2 + m) < (unsigned)HW_) ? 1.f : 0.f;

  f32x4 acc3[4][4];
#pragma unroll
  for (int a = 0; a < 4; ++a)
#pragma unroll
    for (int n = 0; n < 4; ++n) acc3[a][n] = 0.f;

  const float* karrL = (const float*)(smem + KOFF);

  for (int cc = 0; cc < 8; ++cc) {
    const bf16x8 wa0 = *(const bf16x8*)((const char*)wiA + ((cc * 2 + 0) * 4 + q) * 256 + m * 16);
    const bf16x8 wa1 = *(const bf16x8*)((const char*)wiA + ((cc * 2 + 1) * 4 + q) * 256 + m * 16);
    // proj_out B-frags: py-invariant -> hoisted (round-3 reloaded them 4x)
    const bf16x8 wb0 = *(const bf16x8*)((const char*)woB + (((cc * 4 + q) * 64) + 0 * 16 + m) * 16);
    const bf16x8 wb1 = *(const bf16x8*)((const char*)woB + (((cc * 4 + q) * 64) + 1 * 16 + m) * 16);
    const bf16x8 wb2 = *(const bf16x8*)((const char*)woB + (((cc * 4 + q) * 64) + 2 * 16 + m) * 16);
    const bf16x8 wb3 = *(const bf16x8*)((const char*)woB + (((cc * 4 + q) * 64) + 3 * 16 + m) * 16);
    const f32x4 bin4 = *(const f32x4*)(b_in + cc * 16 + q * 4);
    f32x4 kv[9];
#pragma unroll
    for (int tp = 0; tp < 9; ++tp)
      kv[tp] = *(const f32x4*)(karrL + tp * HID_ + cc * 16 + q * 4);

    f32x4 hwin[3][3];
#pragma unroll
    for (int rr = 0; rr < 6; ++rr) {
      const int row = wv * 4 + rr;
      const char* rbase = smem + row * XROWB + q * 288 + m * 16;
      bf16x8 x0L = *(const bf16x8*)(rbase);
      bf16x8 x0M = *(const bf16x8*)(rbase + 16);
      bf16x8 x0R = *(const bf16x8*)(rbase + 32);
      bf16x8 x1L = *(const bf16x8*)(rbase + 1152);
      bf16x8 x1M = *(const bf16x8*)(rbase + 1152 + 16);
      bf16x8 x1R = *(const bf16x8*)(rbase + 1152 + 32);
      f32x4 z = 0.f;
      f32x4 hL = __builtin_amdgcn_mfma_f32_16x16x32_bf16(wa0, x0L, z, 0, 0, 0);
      hL = __builtin_amdgcn_mfma_f32_16x16x32_bf16(wa1, x1L, hL, 0, 0, 0);
      f32x4 hM = __builtin_amdgcn_mfma_f32_16x16x32_bf16(wa0, x0M, z, 0, 0, 0);
      hM = __builtin_amdgcn_mfma_f32_16x16x32_bf16(wa1, x1M, hM, 0, 0, 0);
      f32x4 hR = __builtin_amdgcn_mfma_f32_16x16x32_bf16(wa0, x0R, z, 0, 0, 0);
      hR = __builtin_amdgcn_mfma_f32_16x16x32_bf16(wa1, x1R, hR, 0, 0, 0);
      if ((unsigned)(rowg0 + row) < (unsigned)HW_) {   // wave-uniform
        hL += bin4 * mL;
        hM += bin4 * mM;
        hR += bin4 * mR;
      }
      const int slot = rr % 3;
      hwin[slot][0] = hL; hwin[slot][1] = hM; hwin[slot][2] = hR;

      if (rr >= 2) {
        const int py = rr - 2;
        const int s0 = py % 3, s1 = (py + 1) % 3, s2 = (py + 2) % 3;
        bf16 yf[4];
#pragma unroll
        for (int r = 0; r < 4; ++r) {
          float v = kv[0][r] * hwin[s0][0][r] + kv[1][r] * hwin[s0][1][r] +
                    kv[2][r] * hwin[s0][2][r] + kv[3][r] * hwin[s1][0][r] +
                    kv[4][r] * hwin[s1][1][r] + kv[5][r] * hwin[s1][2][r] +
                    kv[6][r] * hwin[s2][0][r] + kv[7][r] * hwin[s2][1][r] +
                    kv[8][r] * hwin[s2][2][r];
          v = fmaxf(v, 0.1f * v);                     // LeakyReLU(0.1)
          yf[r] = (bf16)v;
        }
        bf16x8 af = {yf[0], yf[1], yf[2], yf[3],
                     (bf16)0.f, (bf16)0.f, (bf16)0.f, (bf16)0.f};
        acc3[py][0] = __builtin_amdgcn_mfma_f32_16x16x32_bf16(af, wb0, acc3[py][0], 0, 0, 0);
        acc3[py][1] = __builtin_amdgcn_mfma_f32_16x16x32_bf16(af, wb1, acc3[py][1], 0, 0, 0);
        acc3[py][2] = __builtin_amdgcn_mfma_f32_16x16x32_bf16(af, wb2, acc3[py][2], 0, 0, 0);
        acc3[py][3] = __builtin_amdgcn_mfma_f32_16x16x32_bf16(af, wb3, acc3[py][3], 0, 0, 0);
      }
    }
  }
  __syncthreads();          // x_s / karr dead; bounce region reuses smem

  // ---- store via LDS bounce: aligned 64B f32x4 rows ----------------------
  float* smemF = (float*)smem;                      // [j][132] f32, halves of 8 rows
  const int c4 = t & 3, js = (t >> 2) & 63;
  const float bo = b_out[js];
  float* obase = out + ((size_t)(b * DIM_ + js) * HW_ + (ty * 16)) * HW_ + tx * 16 + c4 * 4;
#pragma unroll
  for (int half = 0; half < 2; ++half) {
    if ((wv >> 1) == half) {
#pragma unroll
      for (int py = 0; py < 4; ++py) {
        const int lrow = (wv * 4 + py) & 7;
#pragma unroll
        for (int nt = 0; nt < 4; ++nt)
          *(f32x4*)(smemF + (nt * 16 + m) * 132 + lrow * 16 + q * 4) = acc3[py][nt];
      }
    }
    __syncthreads();
#pragma unroll
    for (int lrow = 0; lrow < 8; ++lrow) {
      f32x4 v = *(const f32x4*)(smemF + js * 132 + lrow * 16 + c4 * 4);
      v += bo;
      *(f32x4*)(obase + (size_t)(half * 8 + lrow) * HW_) = v;
    }
    __syncthreads();
  }
}

// ---------------------------------------------------------------------------
extern "C" void kernel_launch(void* const* d_in, const int* in_sizes, int n_in,
                              void* d_out, int out_size, void* d_ws,
                              size_t ws_size, hipStream_t stream) {
  const float* x     = (const float*)d_in[0];
  const float* w_in  = (const float*)d_in[1];
  const float* b_in  = (const float*)d_in[2];
  const float* wg1   = (const float*)d_in[3];
  const float* bg1   = (const float*)d_in[4];
  const float* wg2   = (const float*)d_in[5];
  const float* bg2   = (const float*)d_in[6];
  const float* w_out = (const float*)d_in[7];
  const float* b_out = (const float*)d_in[8];
  float* out = (float*)d_out;

  char* ws = (char*)d_ws;
  bf16*  xT   = (bf16*)(ws + WS_XT);
  float* xsum = (float*)(ws + WS_XSUM);
  float* karr = (float*)(ws + WS_KARR);
  bf16*  wiA  = (bf16*)(ws + WS_WIA);
  bf16*  woB  = (bf16*)(ws + WS_WOB);

  hipMemsetAsync(xsum, 0, B_ * DIM_ * sizeof(float), stream);
  dt_prepw<<<dim3(96), dim3(256), 0, stream>>>(w_in, w_out, wiA, woB);
  dt_prepx<<<dim3(PW_, B_), dim3(256), 0, stream>>>(x, xT, xsum);
  dt_kgen<<<dim3(B_), dim3(128), 0, stream>>>(xsum, w_in, b_in, wg1, bg1, wg2,
                                              bg2, karr);
  dt_kmain<<<dim3(12, 12, B_), dim3(256), 0, stream>>>(xT, wiA, woB, karr,
                                                       b_in, b_out, out);
}